// Round 7
// baseline (621.589 us; speedup 1.0000x reference)
//
#include <hip/hip_runtime.h>

// Problem constants: B=512, T=4096, C=7, H=3 ; N = 2,097,152 rows
constexpr long long N_ROWS = 512LL * 4096LL;
constexpr int BLOCK = 256;                 // 4 waves
constexpr int RPT   = 4;                   // rows per thread (keeps all loads 16B-aligned)
constexpr int NBLOCKS = (int)(N_ROWS / ((long long)BLOCK * RPT));  // 2048

// R7 = R5's main (best-scored: direct-to-register, 16B-aligned quad-row loads)
// + fused last-block final reduction (kills the 1-block reduce dispatch tail).
//
// Session evidence (R0/R1/R5/R6): delivered read BW pins at 2.6-2.8 TB/s across
// 4 structures spanning 4x concurrency, drain-vs-counted-vmcnt sync, 17-54%
// occupancy, warm == cold L3. Main (~85 us) is at a read-path service-rate wall;
// the only remaining controllable cost is the serial reduce dispatch + launch gap.
//
// R2 post-mortem (fused reduce): the arrival counter MUST start at 0 so the
// wrap fires on the true LAST arrival — a poisoned counter made an early block
// reduce stale partials (n_valid short by exactly 512*512). Fix: stream-ordered
// hipMemsetAsync(cnt,0,4,stream) before launch (capture-legal; only
// alloc/free/sync APIs are forbidden in kernel_launch).
__global__ __launch_bounds__(BLOCK) void shortloss_main(
    const float* __restrict__ out0,
    const float* __restrict__ out1,
    const float* __restrict__ out2,
    const int*   __restrict__ labels,   // [N,3] int32
    const float* __restrict__ mask,     // [N]
    const float* __restrict__ reward,   // [N,3]
    float4*      __restrict__ partials, // [NBLOCKS]
    unsigned*    __restrict__ cnt,      // arrival counter, memset to 0 pre-launch
    float*       __restrict__ out)      // [3]
{
    const int tid = threadIdx.x;
    const long long g = (long long)blockIdx.x * BLOCK + tid;   // quad-row index

    // ---------- issue loads (R5 path, verified) ----------
    const float4* p0 = (const float4*)out0 + 7 * g;
    const float4* p1 = (const float4*)out1 + 7 * g;
    const float4* p2 = (const float4*)out2 + 7 * g;
    float4 t[21];                      // 21 x dwordx4, constant-indexed -> registers
    #pragma unroll
    for (int j = 0; j < 7; ++j) t[j]      = p0[j];
    #pragma unroll
    for (int j = 0; j < 7; ++j) t[7 + j]  = p1[j];
    #pragma unroll
    for (int j = 0; j < 7; ++j) t[14 + j] = p2[j];

    int4 lv[3];
    float4 rv[3];
    {
        const int4*   lp = (const int4*)labels  + 3 * g;
        const float4* rp = (const float4*)reward + 3 * g;
        #pragma unroll
        for (int j = 0; j < 3; ++j) lv[j] = lp[j];
        #pragma unroll
        for (int j = 0; j < 3; ++j) rv[j] = rp[j];
    }
    float4 mkv = ((const float4*)mask)[g];

    __builtin_amdgcn_sched_barrier(0);

    // ---------- unpack side data ----------
    const float mk[4] = {mkv.x, mkv.y, mkv.z, mkv.w};
    int lb[12];
    float rw[12];
    #pragma unroll
    for (int j = 0; j < 3; ++j) {
        lb[4*j+0] = lv[j].x; lb[4*j+1] = lv[j].y; lb[4*j+2] = lv[j].z; lb[4*j+3] = lv[j].w;
        rw[4*j+0] = rv[j].x; rw[4*j+1] = rv[j].y; rw[4*j+2] = rv[j].z; rw[4*j+3] = rv[j].w;
    }

    // ---------- per-head row math (register-local) ----------
    float lsum[4] = {0.f, 0.f, 0.f, 0.f};
    int   ok[4]   = {1, 1, 1, 1};
    #pragma unroll
    for (int h = 0; h < 3; ++h) {
        float o[28];
        #pragma unroll
        for (int j = 0; j < 7; ++j) {
            o[4*j+0] = t[7*h+j].x; o[4*j+1] = t[7*h+j].y;
            o[4*j+2] = t[7*h+j].z; o[4*j+3] = t[7*h+j].w;
        }
        #pragma unroll
        for (int i = 0; i < 4; ++i) {
            const int lbl = lb[3*i + h];
            const float* v = o + 7*i;

            // argmax, strict > (first-max tie-break, matches jnp.argmax)
            float best = v[0]; int bestc = 0;
            #pragma unroll
            for (int cc = 1; cc < 7; ++cc)
                if (v[cc] > best) { best = v[cc]; bestc = cc; }

            // gather true-class prob via select chain (no dynamic reg index)
            float opv = v[0];
            #pragma unroll
            for (int cc = 1; cc < 7; ++cc)
                opv = (lbl == cc) ? v[cc] : opv;

            lsum[i] += __logf(opv) * rw[3*i + h];
            ok[i]   &= (bestc == lbl) ? 1 : 0;
        }
    }

    float L = 0.0f;
    int   C = 0, V = 0;
    #pragma unroll
    for (int i = 0; i < 4; ++i) {
        const bool valid = mk[i] < 0.5f;
        V += valid ? 1 : 0;
        L += valid ? lsum[i] : 0.0f;
        C += (valid && ok[i]) ? 1 : 0;
    }

    // ---------- block reduction (proven path) ----------
    #pragma unroll
    for (int off = 32; off > 0; off >>= 1) {
        L += __shfl_down(L, off, 64);
        C += __shfl_down(C, off, 64);
        V += __shfl_down(V, off, 64);
    }
    __shared__ float sL[BLOCK / 64];
    __shared__ int   sC[BLOCK / 64], sV[BLOCK / 64];
    const int wave = tid >> 6;
    if ((tid & 63) == 0) { sL[wave] = L; sC[wave] = C; sV[wave] = V; }
    __syncthreads();
    if (tid == 0) {
        float l = 0.0f; int cc = 0, vv = 0;
        #pragma unroll
        for (int w = 0; w < BLOCK / 64; ++w) { l += sL[w]; cc += sC[w]; vv += sV[w]; }
        partials[blockIdx.x] = make_float4(l, (float)cc, (float)vv, 0.0f);
    }

    // ---------- fused final reduction: LAST block to arrive does it ----------
    // Release: tid0's partials store -> threadfence -> device-scope atomicAdd.
    __threadfence();
    __shared__ int amLast;
    if (tid == 0) {
        unsigned old = atomicAdd(cnt, 1u);   // device-scope by default (m20)
        amLast = (old + 1u == (unsigned)NBLOCKS) ? 1 : 0;
    }
    __syncthreads();
    if (amLast) {
        __threadfence();                     // acquire all blocks' partials
        float l = 0.f, c = 0.f, v = 0.f;
        #pragma unroll
        for (int k = 0; k < NBLOCKS / BLOCK; ++k) {   // 8 per thread
            float4 p = partials[tid + BLOCK * k];
            l += p.x; c += p.y; v += p.z;
        }
        #pragma unroll
        for (int off = 32; off > 0; off >>= 1) {
            l += __shfl_down(l, off, 64);
            c += __shfl_down(c, off, 64);
            v += __shfl_down(v, off, 64);
        }
        __shared__ float rL[BLOCK / 64], rC[BLOCK / 64], rV[BLOCK / 64];
        if ((tid & 63) == 0) { rL[wave] = l; rC[wave] = c; rV[wave] = v; }
        __syncthreads();
        if (tid == 0) {
            float fl = 0.f, fc = 0.f, fv = 0.f;
            #pragma unroll
            for (int w = 0; w < BLOCK / 64; ++w) { fl += rL[w]; fc += rC[w]; fv += rV[w]; }
            out[0] = -fl / fv;
            out[1] = fc;
            out[2] = fv;
        }
    }
}

extern "C" void kernel_launch(void* const* d_in, const int* in_sizes, int n_in,
                              void* d_out, int out_size, void* d_ws, size_t ws_size,
                              hipStream_t stream) {
    const float* out0   = (const float*)d_in[0];
    const float* out1   = (const float*)d_in[1];
    const float* out2   = (const float*)d_in[2];
    const int*   labels = (const int*)  d_in[3];
    const float* mask   = (const float*)d_in[4];
    const float* reward = (const float*)d_in[5];

    float4*   partials = (float4*)d_ws;                       // 2048 * 16 B = 32 KB
    unsigned* cnt      = (unsigned*)((char*)d_ws + NBLOCKS * sizeof(float4));

    // Arrival counter MUST start at 0 (R2 post-mortem). Stream-ordered memset
    // is graph-capture-legal; only alloc/free/sync APIs are forbidden here.
    hipMemsetAsync(cnt, 0, sizeof(unsigned), stream);

    shortloss_main<<<NBLOCKS, BLOCK, 0, stream>>>(
        out0, out1, out2, labels, mask, reward, partials, cnt, (float*)d_out);
}

// Round 8
// 260.047 us; speedup vs baseline: 2.3903x; 2.3903x over previous
//
#include <hip/hip_runtime.h>

// Problem constants: B=512, T=4096, C=7, H=3 ; N = 2,097,152 rows
constexpr long long N_ROWS = 512LL * 4096LL;
constexpr int BLOCK = 256;                 // 4 waves
constexpr int RPT   = 4;                   // rows per thread (keeps all loads 16B-aligned)
constexpr int NBLOCKS = (int)(N_ROWS / ((long long)BLOCK * RPT));  // 2048

// R8 = R5's main (best-scored, 223.8 us: direct-to-register 16B-aligned quad-row
// loads; main ~85 us at the measured 2.6-2.8 TB/s delivered-BW wall) + FENCE-FREE
// fused final reduction.
//
// R7 post-mortem: __threadfence() on the all-blocks path = device-scope L2
// writeback/invalidate per wave (per-XCD L2s are non-coherent) -> 8192 L2
// flushes serialized the memory system chip-wide (main 85->492 us, FETCH
// unchanged -> latency storm, not traffic). NEVER fence the hot path.
//
// Fence-free scheme: device-scope atomics execute at the device-coherent point
// (bypassing non-coherent L2s — learn_hip m20), so ordering needs no cache
// maintenance. Per block, tid0 only:
//   atomicAdd(accL/accC/accV) ; s_waitcnt vmcnt(0) ; old = atomicAdd(cnt,1)
// Last arrival reads totals back VIA ATOMICS (fetch-add of 0 — served at the
// coherent point, cannot be stale) and writes out. ~4 atomics/block, no fences.
// cnt+accumulators (16 B) memset to 0 pre-launch (capture-legal, proven in R7).
__global__ __launch_bounds__(BLOCK) void shortloss_main(
    const float* __restrict__ out0,
    const float* __restrict__ out1,
    const float* __restrict__ out2,
    const int*   __restrict__ labels,   // [N,3] int32
    const float* __restrict__ mask,     // [N]
    const float* __restrict__ reward,   // [N,3]
    float*       __restrict__ accL,     // ws+0  : float accumulator
    unsigned*    __restrict__ accC,     // ws+4  : uint accumulator
    unsigned*    __restrict__ accV,     // ws+8  : uint accumulator
    unsigned*    __restrict__ cnt,      // ws+12 : arrival counter
    float*       __restrict__ out)      // [3]
{
    const int tid = threadIdx.x;
    const long long g = (long long)blockIdx.x * BLOCK + tid;   // quad-row index

    // ---------- issue loads (R5 path, verified) ----------
    const float4* p0 = (const float4*)out0 + 7 * g;
    const float4* p1 = (const float4*)out1 + 7 * g;
    const float4* p2 = (const float4*)out2 + 7 * g;
    float4 t[21];                      // 21 x dwordx4, constant-indexed -> registers
    #pragma unroll
    for (int j = 0; j < 7; ++j) t[j]      = p0[j];
    #pragma unroll
    for (int j = 0; j < 7; ++j) t[7 + j]  = p1[j];
    #pragma unroll
    for (int j = 0; j < 7; ++j) t[14 + j] = p2[j];

    int4 lv[3];
    float4 rv[3];
    {
        const int4*   lp = (const int4*)labels  + 3 * g;
        const float4* rp = (const float4*)reward + 3 * g;
        #pragma unroll
        for (int j = 0; j < 3; ++j) lv[j] = lp[j];
        #pragma unroll
        for (int j = 0; j < 3; ++j) rv[j] = rp[j];
    }
    float4 mkv = ((const float4*)mask)[g];

    __builtin_amdgcn_sched_barrier(0);

    // ---------- unpack side data ----------
    const float mk[4] = {mkv.x, mkv.y, mkv.z, mkv.w};
    int lb[12];
    float rw[12];
    #pragma unroll
    for (int j = 0; j < 3; ++j) {
        lb[4*j+0] = lv[j].x; lb[4*j+1] = lv[j].y; lb[4*j+2] = lv[j].z; lb[4*j+3] = lv[j].w;
        rw[4*j+0] = rv[j].x; rw[4*j+1] = rv[j].y; rw[4*j+2] = rv[j].z; rw[4*j+3] = rv[j].w;
    }

    // ---------- per-head row math (register-local) ----------
    float lsum[4] = {0.f, 0.f, 0.f, 0.f};
    int   ok[4]   = {1, 1, 1, 1};
    #pragma unroll
    for (int h = 0; h < 3; ++h) {
        float o[28];
        #pragma unroll
        for (int j = 0; j < 7; ++j) {
            o[4*j+0] = t[7*h+j].x; o[4*j+1] = t[7*h+j].y;
            o[4*j+2] = t[7*h+j].z; o[4*j+3] = t[7*h+j].w;
        }
        #pragma unroll
        for (int i = 0; i < 4; ++i) {
            const int lbl = lb[3*i + h];
            const float* v = o + 7*i;

            // argmax, strict > (first-max tie-break, matches jnp.argmax)
            float best = v[0]; int bestc = 0;
            #pragma unroll
            for (int cc = 1; cc < 7; ++cc)
                if (v[cc] > best) { best = v[cc]; bestc = cc; }

            // gather true-class prob via select chain (no dynamic reg index)
            float opv = v[0];
            #pragma unroll
            for (int cc = 1; cc < 7; ++cc)
                opv = (lbl == cc) ? v[cc] : opv;

            lsum[i] += __logf(opv) * rw[3*i + h];
            ok[i]   &= (bestc == lbl) ? 1 : 0;
        }
    }

    float L = 0.0f;
    int   C = 0, V = 0;
    #pragma unroll
    for (int i = 0; i < 4; ++i) {
        const bool valid = mk[i] < 0.5f;
        V += valid ? 1 : 0;
        L += valid ? lsum[i] : 0.0f;
        C += (valid && ok[i]) ? 1 : 0;
    }

    // ---------- block reduction (proven path) ----------
    #pragma unroll
    for (int off = 32; off > 0; off >>= 1) {
        L += __shfl_down(L, off, 64);
        C += __shfl_down(C, off, 64);
        V += __shfl_down(V, off, 64);
    }
    __shared__ float sL[BLOCK / 64];
    __shared__ int   sC[BLOCK / 64], sV[BLOCK / 64];
    const int wave = tid >> 6;
    if ((tid & 63) == 0) { sL[wave] = L; sC[wave] = C; sV[wave] = V; }
    __syncthreads();

    // ---------- fence-free fused reduction (tid0 only) ----------
    if (tid == 0) {
        float l = 0.0f; int cc = 0, vv = 0;
        #pragma unroll
        for (int w = 0; w < BLOCK / 64; ++w) { l += sL[w]; cc += sC[w]; vv += sV[w]; }

        atomicAdd(accL, l);
        atomicAdd(accC, (unsigned)cc);
        atomicAdd(accV, (unsigned)vv);
        // Order my value-adds to the coherent point before signaling arrival.
        asm volatile("s_waitcnt vmcnt(0)" ::: "memory");
        unsigned old = atomicAdd(cnt, 1u);
        if (old + 1u == (unsigned)NBLOCKS) {
            // All arrivals' value-adds are at the coherent point. Read totals
            // back via atomics (served at the coherent point -> never stale).
            float    fl = atomicAdd(accL, 0.0f);
            unsigned fc = atomicAdd(accC, 0u);
            unsigned fv = atomicAdd(accV, 0u);
            out[0] = -fl / (float)fv;
            out[1] = (float)fc;
            out[2] = (float)fv;
        }
    }
}

extern "C" void kernel_launch(void* const* d_in, const int* in_sizes, int n_in,
                              void* d_out, int out_size, void* d_ws, size_t ws_size,
                              hipStream_t stream) {
    const float* out0   = (const float*)d_in[0];
    const float* out1   = (const float*)d_in[1];
    const float* out2   = (const float*)d_in[2];
    const int*   labels = (const int*)  d_in[3];
    const float* mask   = (const float*)d_in[4];
    const float* reward = (const float*)d_in[5];

    float*    accL = (float*)d_ws;
    unsigned* accC = (unsigned*)((char*)d_ws + 4);
    unsigned* accV = (unsigned*)((char*)d_ws + 8);
    unsigned* cnt  = (unsigned*)((char*)d_ws + 12);

    // Accumulators + arrival counter MUST start at 0 (R2 post-mortem).
    // Stream-ordered memset is graph-capture-legal (proven in R7).
    hipMemsetAsync(d_ws, 0, 16, stream);

    shortloss_main<<<NBLOCKS, BLOCK, 0, stream>>>(
        out0, out1, out2, labels, mask, reward, accL, accC, accV, cnt, (float*)d_out);
}